// Round 10
// baseline (93.451 us; speedup 1.0000x reference)
//
#include <hip/hip_runtime.h>
#include <hip/hip_bf16.h>
#include <stdint.h>

typedef unsigned short u16;
typedef __attribute__((ext_vector_type(4))) float f32x4;
typedef __attribute__((ext_vector_type(8))) short bf16x8;

#define DEV __device__ __forceinline__

DEV float bf2f(u16 b){ unsigned u = ((unsigned)b) << 16; return __builtin_bit_cast(float, u); }
DEV u16 f2bf(float f){
  unsigned u = __builtin_bit_cast(unsigned, f);
  u += 0x7FFFu + ((u >> 16) & 1u);
  return (u16)(u >> 16);
}

// XCD-aware block swizzle (T1). Requires nwg % 8 == 0.
DEV int xcd_swz(int nwg){
  const int bid = (int)blockIdx.x;
  return (bid & 7) * (nwg >> 3) + (bid >> 3);
}

DEV void gld16(const u16* src, u16* dst){
  __builtin_amdgcn_global_load_lds(
      (const __attribute__((address_space(1))) void*)src,
      (__attribute__((address_space(3))) void*)dst, 16, 0, 0);
}

// stage a 128x64 bf16 tile (row-major lda=64) into LDS, linear dest +
// source-slot XOR pre-swizzle (slots of 8 u16, XOR row&7)
template<int NTH>
DEV void stage_x64(const u16* srcbase, u16* dst, int tid){
  #pragma unroll
  for (int q = 0; q < 16384 / (NTH * 16); q++) {
    const int boff = q * NTH * 16 + tid * 16;
    const int row = boff >> 7, slot = (boff & 127) >> 4;
    const int kk = (slot ^ (row & 7)) << 3;
    gld16(srcbase + (long)row * 64 + kk, dst + (boff >> 1));
  }
}

// 64x64-tile transpose helper: dst[c][r] = src[r][c] (f32 -> bf16)
DEV void tr_tile(float (*tile)[65], const float* src, u16* dst,
                 int R, int C, int r0, int c0)
{
  const int t = threadIdx.x;
  const int rr = t >> 2, cc = (t & 3) * 16;
  const float* sp = src + (long)(r0 + rr) * C + (c0 + cc);
  #pragma unroll
  for (int q = 0; q < 16; q++) tile[rr][cc + q] = sp[q];
  __syncthreads();
  u16* dp = dst + (long)(c0 + rr) * R + (r0 + cc);
  #pragma unroll
  for (int q = 0; q < 16; q++) dp[q] = f2bf(tile[cc + q][rr]);
}

// ---------------------------------------------------------------------------
// Consolidated prep: Wp->bf16 | x^T | Wo^T | uh | x->xb(+ones) | nh row of MxT
__global__ __launch_bounds__(256) void k_misc(
    const float* __restrict__ x, const float* __restrict__ Wp,
    const float* __restrict__ Wo, const float* __restrict__ bp,
    u16* __restrict__ xt, u16* __restrict__ Wot, u16* __restrict__ Wpb,
    u16* __restrict__ xb, float* __restrict__ uh, u16* __restrict__ MxT)
{
  __shared__ float tile[64][65];
  const int q = blockIdx.x;
  if (q < 240) {                      // Wp -> Wpb (bf16 flat cast)
    const long i = (long)q * 256 + threadIdx.x;
    const f32x4 a = *(const f32x4*)(Wp + i * 8);
    const f32x4 b = *(const f32x4*)(Wp + i * 8 + 4);
    bf16x8 r;
    #pragma unroll
    for (int e = 0; e < 4; e++){ r[e] = (short)f2bf(a[e]); r[e+4] = (short)f2bf(b[e]); }
    *(bf16x8*)(Wpb + i * 8) = r;
  } else if (q < 368) {               // x -> xt (per-batch 64x1024 transpose)
    const int p = q - 240, c0 = (p & 15) * 64, b = p >> 4;
    tr_tile(tile, x + (long)b * 65536, xt + (long)b * 65536, 64, 1024, 0, c0);
  } else if (q < 408) {               // Wo -> Wot
    const int p = q - 368;
    tr_tile(tile, Wo, Wot, 2560, 64, p * 64, 0);
  } else if (q < 472) {               // uh[h][c] = Wq[c] . bk (one wave each)
    const int p = q - 408;
    const int wv = threadIdx.x >> 6, lane = threadIdx.x & 63;
    const int idx = p * 4 + wv;       // 0..255
    const int h = idx >> 6, c = idx & 63;
    const int qb = h * 1920, kb = qb + 640;
    const float* wrow = Wp + (long)c * 7680 + qb;
    float s = 0.f;
    #pragma unroll
    for (int d0 = 0; d0 < 640; d0 += 64)
      s += wrow[d0 + lane] * bp[kb + d0 + lane];
    #pragma unroll
    for (int off = 32; off; off >>= 1) s += __shfl_down(s, off);
    if (lane == 0) uh[idx] = s;
  } else if (q < 792) {               // x -> xb [8][80][1024]; row64=1, 65-79=0
    const int ch = (q - 472) * 256 + threadIdx.x;     // 81920 chunks of 8
    const int b = ch / 10240, rem = ch % 10240;
    const int row = rem >> 7, j8 = rem & 127;
    bf16x8 r;
    if (row < 64) {
      const float* sp = x + ((long)b * 64 + row) * 1024 + j8 * 8;
      const f32x4 a = *(const f32x4*)sp;
      const f32x4 bb = *(const f32x4*)(sp + 4);
      #pragma unroll
      for (int e = 0; e < 4; e++){ r[e] = (short)f2bf(a[e]); r[e+4] = (short)f2bf(bb[e]); }
    } else if (row == 64) {
      #pragma unroll
      for (int e = 0; e < 8; e++) r[e] = (short)0x3F80;   // 1.0 bf16
    } else {
      #pragma unroll
      for (int e = 0; e < 8; e++) r[e] = 0;
    }
    *(bf16x8*)(xb + ((long)b * 80 + row) * 1024 + j8 * 8) = r;
  } else {                            // nh: MxT[c'][h*80+64] = bv . Wo[:,c']
    const int wv = threadIdx.x >> 6, lane = threadIdx.x & 63;  // wv = h, lane = c'
    const float* bv = bp + wv * 1920 + 1280;
    float s = 0.f;
    #pragma unroll 8
    for (int d = 0; d < 640; d++)
      s += Wo[(long)(wv * 640 + d) * 64 + lane] * bv[d];
    MxT[lane * 320 + wv * 80 + 64] = f2bf(s);
    #pragma unroll
    for (int e = 1; e < 16; e++) MxT[lane * 320 + wv * 80 + 64 + e] = 0;
  }
}

// ---------------------------------------------------------------------------
// NT GEMM tile core, 2-phase double-buffered + both-sides XOR swizzle.
template<int BM, int BN, int BK, int WR, int WC, int MF, int NF>
DEV void gemm_nt(const u16* __restrict__ A, const u16* __restrict__ B,
                 int K, long lda, long ldb, int arow0, int brow0,
                 f32x4 (&acc)[MF][NF], u16* As, u16* Bs)
{
  const int tid  = threadIdx.x;
  const int lane = tid & 63;
  const int w    = tid >> 6;
  const int wr   = w / WC, wc = w % WC;
  constexpr int NT   = WR * WC * 64;
  constexpr int AISS = (BM * BK * 2) / (NT * 16);
  constexpr int BISS = (BN * BK * 2) / (NT * 16);
  constexpr int ABUF = BM * BK;
  constexpr int BBUF = BN * BK;

  #pragma unroll
  for (int m = 0; m < MF; m++)
    #pragma unroll
    for (int n = 0; n < NF; n++) acc[m][n] = f32x4{0.f, 0.f, 0.f, 0.f};

  const int frow = lane & 15;
  const int fs   = lane >> 4;

  auto stage = [&](int buf, int kt) {
    #pragma unroll
    for (int q = 0; q < AISS; q++) {
      const int boff = q * NT * 16 + tid * 16;
      const int row  = boff / (BK * 2);
      const int slot = (boff % (BK * 2)) >> 4;
      const int kk   = ((slot ^ (row & 7)) << 3);
      gld16(A + (long)(arow0 + row) * lda + kt + kk, As + buf * ABUF + (boff >> 1));
    }
    #pragma unroll
    for (int q = 0; q < BISS; q++) {
      const int boff = q * NT * 16 + tid * 16;
      const int row  = boff / (BK * 2);
      const int slot = (boff % (BK * 2)) >> 4;
      const int kk   = ((slot ^ (row & 7)) << 3);
      gld16(B + (long)(brow0 + row) * ldb + kt + kk, Bs + buf * BBUF + (boff >> 1));
    }
  };

  auto compute = [&](int buf) {
    __builtin_amdgcn_s_setprio(1);
    #pragma unroll
    for (int ks = 0; ks < BK / 32; ++ks) {
      bf16x8 af[MF], bfr[NF];
      #pragma unroll
      for (int m = 0; m < MF; m++) {
        const int row  = wr * (MF * 16) + m * 16 + frow;
        const int slot = (ks * 4 + fs) ^ (row & 7);
        af[m] = *(const bf16x8*)(As + buf * ABUF + row * BK + slot * 8);
      }
      #pragma unroll
      for (int n = 0; n < NF; n++) {
        const int row  = wc * (NF * 16) + n * 16 + frow;
        const int slot = (ks * 4 + fs) ^ (row & 7);
        bfr[n] = *(const bf16x8*)(Bs + buf * BBUF + row * BK + slot * 8);
      }
      #pragma unroll
      for (int m = 0; m < MF; m++)
        #pragma unroll
        for (int n = 0; n < NF; n++)
          acc[m][n] = __builtin_amdgcn_mfma_f32_16x16x32_bf16(af[m], bfr[n], acc[m][n], 0, 0, 0);
    }
    __builtin_amdgcn_s_setprio(0);
  };

  stage(0, 0);
  asm volatile("s_waitcnt vmcnt(0)" ::: "memory");
  __syncthreads();
  int cur = 0;
  for (int kt = BK; kt < K; kt += BK) {
    stage(cur ^ 1, kt);
    compute(cur);
    asm volatile("s_waitcnt vmcnt(0)" ::: "memory");
    __syncthreads();
    cur ^= 1;
  }
  compute(cur);
}

// Per-wave epilogue: stage wave tile into LDS swizzled, coalesced bf16x8 stores
template<int MF, int NF, typename FV, typename FS>
DEV void epi_u16(u16* SH, FV&& fval, FS&& fstore)
{
  constexpr int RC = MF * 16, CC = NF * 16, CPR = NF * 2;
  const int lane = threadIdx.x & 63;
  const int w = threadIdx.x >> 6;
  u16* et = SH + w * (RC * CC);
  __syncthreads();
  #pragma unroll
  for (int m = 0; m < MF; m++)
    #pragma unroll
    for (int n = 0; n < NF; n++)
      #pragma unroll
      for (int j = 0; j < 4; j++) {
        const int row = m * 16 + (lane >> 4) * 4 + j;
        const int col = n * 16 + (lane & 15);
        et[row * CC + (((col >> 3) ^ row) & (CPR - 1)) * 8 + (col & 7)] =
            f2bf(fval(m, n, j, row, col));
      }
  constexpr int RPI = 64 / CPR;
  #pragma unroll
  for (int it = 0; it < RC / RPI; ++it) {
    const int row = it * RPI + lane / CPR;
    const int ch  = lane % CPR;
    bf16x8 v = *(const bf16x8*)(et + row * CC + ((ch ^ row) & (CPR - 1)) * 8);
    fstore(row, ch * 8, v);
  }
}

// ---------------------------------------------------------------------------
// k_prep: blocks 0-3: Ahat[h] = Wk_h @ Wq_h^T; blocks 4-7: MxT = (Wv_h Wo_h)^T
__global__ __launch_bounds__(256) void k_prep(
    const u16* __restrict__ Wpb, const u16* __restrict__ Wot,
    u16* __restrict__ Ahat, u16* __restrict__ MxT)
{
  __shared__ __align__(16) u16 SH[4 * 64 * 64];
  u16* As = SH; u16* Bs = SH + 2 * 64 * 64;
  const int q = blockIdx.x;
  const int w = threadIdx.x >> 6;
  const int wr = w >> 1, wc = w & 1;
  f32x4 acc[2][2];
  if (q < 4) {
    const int h = q;
    gemm_nt<64, 64, 64, 2, 2, 2, 2>(Wpb + h * 1920 + 640, Wpb + h * 1920, 640,
                                    7680, 7680, 0, 0, acc, As, Bs);
    u16* dst = Ahat + h * 4096;
    epi_u16<2, 2>(SH,
      [&](int m, int n, int j, int row, int col){ return acc[m][n][j]; },
      [&](int row, int c0, bf16x8 v){
        *(bf16x8*)(dst + (wr * 32 + row) * 64 + wc * 32 + c0) = v; });
  } else {
    const int h = q - 4;
    gemm_nt<64, 64, 64, 2, 2, 2, 2>(Wot + h * 640, Wpb + h * 1920 + 1280, 640,
                                    2560, 7680, 0, 0, acc, As, Bs);
    epi_u16<2, 2>(SH,
      [&](int m, int n, int j, int row, int col){ return acc[m][n][j]; },
      [&](int row, int c0, bf16x8 v){
        *(bf16x8*)(MxT + (long)(wr * 32 + row) * 320 + h * 80 + wc * 32 + c0) = v; });
  }
}

// ---------------------------------------------------------------------------
// Pass 1: Z[bh][j] = sum_i exp(SCALE*(T_i.x_j + ut_i)). No P store.
// grid 256 = (bh, tj); per block loop over 8 i-tiles, T recomputed in LDS.
__global__ __launch_bounds__(256) void k_qkz(
    const u16* __restrict__ xt, const u16* __restrict__ Ahat,
    const float* __restrict__ uh, float* __restrict__ Z)
{
  __shared__ __align__(16) u16 XI[2][8192];
  __shared__ __align__(16) u16 AH[4096];
  __shared__ __align__(16) u16 XJ[8192];
  __shared__ __align__(16) u16 TT[8192];
  __shared__ float uts[128];
  __shared__ float uhl[64];
  __shared__ float Zs[2][128];
  const int tid = threadIdx.x, lane = tid & 63, w = tid >> 6;
  const int frow = lane & 15, fs = lane >> 4;
  const int wr = w >> 1, wc = w & 1;
  const int id = xcd_swz(256);
  const int bh = id >> 3, tj = id & 7;
  const int b = bh >> 2, h = bh & 3;
  const int j0 = b * 1024 + tj * 128;

  #pragma unroll
  for (int q = 0; q < 2; q++) {       // AH
    const int boff = q * 4096 + tid * 16;
    const int row = boff >> 7, slot = (boff & 127) >> 4;
    const int kk = (slot ^ (row & 7)) << 3;
    gld16(Ahat + h * 4096 + row * 64 + kk, AH + (boff >> 1));
  }
  stage_x64<256>(xt + (long)j0 * 64, XJ, tid);
  stage_x64<256>(xt + (long)(b * 1024) * 64, XI[0], tid);
  if (tid < 64) uhl[tid] = uh[h * 64 + tid];
  asm volatile("s_waitcnt vmcnt(0)" ::: "memory");
  __syncthreads();

  float csum[4] = {0.f, 0.f, 0.f, 0.f};
  int cur = 0;
  for (int it = 0; it < 8; ++it) {
    if (it < 7) stage_x64<256>(xt + (long)(b * 1024 + (it + 1) * 128) * 64, XI[cur ^ 1], tid);
    // T-gemm: T = XI[cur] @ AH^T (wave 64x32)
    f32x4 acc1[4][2];
    #pragma unroll
    for (int m = 0; m < 4; m++)
      #pragma unroll
      for (int n = 0; n < 2; n++) acc1[m][n] = f32x4{0.f, 0.f, 0.f, 0.f};
    #pragma unroll
    for (int ks = 0; ks < 2; ks++) {
      bf16x8 af[4], bfr[2];
      #pragma unroll
      for (int m = 0; m < 4; m++) {
        const int row = wr * 64 + m * 16 + frow;
        af[m] = *(const bf16x8*)(XI[cur] + row * 64 + (((ks * 4 + fs) ^ (row & 7)) << 3));
      }
      #pragma unroll
      for (int n = 0; n < 2; n++) {
        const int row = wc * 32 + n * 16 + frow;
        bfr[n] = *(const bf16x8*)(AH + row * 64 + (((ks * 4 + fs) ^ (row & 7)) << 3));
      }
      #pragma unroll
      for (int m = 0; m < 4; m++)
        #pragma unroll
        for (int n = 0; n < 2; n++)
          acc1[m][n] = __builtin_amdgcn_mfma_f32_16x16x32_bf16(af[m], bfr[n], acc1[m][n], 0, 0, 0);
    }
    float su = 0.f;
    if (tid < 128) {
      #pragma unroll
      for (int s = 0; s < 8; s++) {
        bf16x8 v = *(const bf16x8*)(XI[cur] + tid * 64 + ((s ^ (tid & 7)) << 3));
        #pragma unroll
        for (int e = 0; e < 8; e++) su += bf2f((u16)v[e]) * uhl[s * 8 + e];
      }
    }
    __syncthreads();                 // prev TT/uts reads done
    if (tid < 128) uts[tid] = su;
    #pragma unroll
    for (int m = 0; m < 4; m++)
      #pragma unroll
      for (int n = 0; n < 2; n++)
        #pragma unroll
        for (int j = 0; j < 4; j++) {
          const int row = wr * 64 + m * 16 + (lane >> 4) * 4 + j;
          const int col = wc * 32 + n * 16 + (lane & 15);
          TT[row * 64 + (((col >> 3) ^ (row & 7)) << 3) + (col & 7)] = f2bf(acc1[m][n][j]);
        }
    asm volatile("s_waitcnt vmcnt(0)" ::: "memory");
    __syncthreads();                 // TT/uts visible; XI[cur^1] landed
    // S-gemm + exp + csum
    f32x4 sacc[4][4];
    #pragma unroll
    for (int m = 0; m < 4; m++)
      #pragma unroll
      for (int n = 0; n < 4; n++) sacc[m][n] = f32x4{0.f, 0.f, 0.f, 0.f};
    #pragma unroll
    for (int ks = 0; ks < 2; ks++) {
      bf16x8 af[4], bfr[4];
      #pragma unroll
      for (int m = 0; m < 4; m++) {
        const int row = wr * 64 + m * 16 + frow;
        af[m] = *(const bf16x8*)(TT + row * 64 + (((ks * 4 + fs) ^ (row & 7)) << 3));
      }
      #pragma unroll
      for (int n = 0; n < 4; n++) {
        const int row = wc * 64 + n * 16 + frow;
        bfr[n] = *(const bf16x8*)(XJ + row * 64 + (((ks * 4 + fs) ^ (row & 7)) << 3));
      }
      #pragma unroll
      for (int m = 0; m < 4; m++)
        #pragma unroll
        for (int n = 0; n < 4; n++)
          sacc[m][n] = __builtin_amdgcn_mfma_f32_16x16x32_bf16(af[m], bfr[n], sacc[m][n], 0, 0, 0);
    }
    #pragma unroll
    for (int m = 0; m < 4; m++)
      #pragma unroll
      for (int j = 0; j < 4; j++) {
        const float rv = uts[wr * 64 + m * 16 + (lane >> 4) * 4 + j];
        #pragma unroll
        for (int n = 0; n < 4; n++)
          csum[n] += __expf((sacc[m][n][j] + rv) * 0.03952847075210474f);
      }
    cur ^= 1;
  }
  #pragma unroll
  for (int n = 0; n < 4; n++) {
    csum[n] += __shfl_xor(csum[n], 16);
    csum[n] += __shfl_xor(csum[n], 32);
  }
  if ((lane >> 4) == 0) {
    #pragma unroll
    for (int n = 0; n < 4; n++) Zs[wr][wc * 64 + n * 16 + lane] = csum[n];
  }
  __syncthreads();
  if (tid < 128) Z[(long)bh * 1024 + tj * 128 + tid] = Zs[0][tid] + Zs[1][tid];
}

// ---------------------------------------------------------------------------
// Pass 2: G[b*1024+i][h*80+c] = sum_j (exp(..)/Z[j]) * xb[b][c][j]
// 4 waves (256 threads), grid 256 = (bh, ti).
__global__ __launch_bounds__(256) void k_G(
    const u16* __restrict__ xt, const u16* __restrict__ xb,
    const u16* __restrict__ Ahat, const float* __restrict__ uh,
    const float* __restrict__ Z, u16* __restrict__ G)
{
  __shared__ __align__(16) u16 XIT[8192];    // XI, then T
  __shared__ __align__(16) u16 AH[4096];
  __shared__ __align__(16) u16 XJ[2][8192];
  __shared__ __align__(16) u16 XB[10240];    // [80][128]
  __shared__ __align__(16) u16 PT[16384];    // P-tile [128][128]; then G staging
  __shared__ float uts[128];
  __shared__ float uhl[64];
  __shared__ float rzs[128];
  const int tid = threadIdx.x, lane = tid & 63, w = tid >> 6;
  const int frow = lane & 15, fs = lane >> 4;
  const int wr = w >> 1, wc = w & 1;
  const int id = xcd_swz(256);
  const int bh = id >> 3, ti = id & 7;
  const int b = bh >> 2, h = bh & 3;
  const int i0 = b * 1024 + ti * 128;

  #pragma unroll
  for (int q = 0; q < 2; q++) {       // AH
    const int boff = q * 4096 + tid * 16;
    const int row = boff >> 7, slot = (boff & 127) >> 4;
    const int kk = (slot ^ (row & 7)) << 3;
    gld16(Ahat + h * 4096 + row * 64 + kk, AH + (boff >> 1));
  }
  stage_x64<256>(xt + (long)i0 * 64, XIT, tid);
  stage_x64<256>(xt + (long)(b * 1024) * 64, XJ[0], tid);
  if (tid < 64) uhl[tid] = uh[h * 64 + tid];
  asm volatile("s_waitcnt vmcnt(0)" ::: "memory");
  __syncthreads();

  // T-gemm + ut
  f32x4 acc1[4][2];
  #pragma unroll
  for (int m = 0; m < 4; m++)
    #pragma unroll
    for (int n = 0; n < 2; n++) acc1[m][n] = f32x4{0.f, 0.f, 0.f, 0.f};
  #pragma unroll
  for (int ks = 0; ks < 2; ks++) {
    bf16x8 af[4], bfr[2];
    #pragma unroll
    for (int m = 0; m < 4; m++) {
      const int row = wr * 64 + m * 16 + frow;
      af[m] = *(const bf16x8*)(XIT + row * 64 + (((ks * 4 + fs) ^ (row & 7)) << 3));
    }
    #pragma unroll
    for (int n = 0; n < 2; n++) {
      const int row = wc * 32 + n * 16 + frow;
      bfr[n] = *(const bf16x8*)(AH + row * 64 + (((ks * 4 + fs) ^ (row & 7)) << 3));
    }
    #pragma unroll
    for (int m = 0; m < 4; m++)
      #pragma unroll
      for (int n = 0; n < 2; n++)
        acc1[m][n] = __builtin_amdgcn_mfma_f32_16x16x32_bf16(af[m], bfr[n], acc1[m][n], 0, 0, 0);
  }
  float su = 0.f;
  if (tid < 128) {
    #pragma unroll
    for (int s = 0; s < 8; s++) {
      bf16x8 v = *(const bf16x8*)(XIT + tid * 64 + ((s ^ (tid & 7)) << 3));
      #pragma unroll
      for (int e = 0; e < 8; e++) su += bf2f((u16)v[e]) * uhl[s * 8 + e];
    }
  }
  __syncthreads();                   // all XIT reads done
  if (tid < 128) uts[tid] = su;
  #pragma unroll
  for (int m = 0; m < 4; m++)        // write T over XIT
    #pragma unroll
    for (int n = 0; n < 2; n++)
      #pragma unroll
      for (int j = 0; j < 4; j++) {
        const int row = wr * 64 + m * 16 + (lane >> 4) * 4 + j;
        const int col = wc * 32 + n * 16 + (lane & 15);
        XIT[row * 64 + (((col >> 3) ^ (row & 7)) << 3) + (col & 7)] = f2bf(acc1[m][n][j]);
      }
  __syncthreads();                   // T/uts visible

  f32x4 gacc[2][5];
  #pragma unroll
  for (int m = 0; m < 2; m++)
    #pragma unroll
    for (int n = 0; n < 5; n++) gacc[m][n] = f32x4{0.f, 0.f, 0.f, 0.f};
  int cur = 0;
  for (int j = 0; j < 8; ++j) {
    // stage XB(j): [80][128] from xb[b][c][j*128..]
    #pragma unroll
    for (int q = 0; q < 5; q++) {
      const int boff = q * 4096 + tid * 16;
      const int c = boff >> 8, sl = (boff & 255) >> 4;
      const int kk = (sl ^ (c & 7)) << 3;
      gld16(xb + ((long)b * 80 + c) * 1024 + j * 128 + kk, XB + (boff >> 1));
    }
    if (j < 7) stage_x64<256>(xt + (long)(b * 1024 + (j + 1) * 128) * 64, XJ[cur ^ 1], tid);
    if (tid < 128) rzs[tid] = 1.0f / Z[(long)bh * 1024 + j * 128 + tid];
    // S-gemm: S = T @ XJ[cur]^T (wave 64x64)
    f32x4 sacc[4][4];
    #pragma unroll
    for (int m = 0; m < 4; m++)
      #pragma unroll
      for (int n = 0; n < 4; n++) sacc[m][n] = f32x4{0.f, 0.f, 0.f, 0.f};
    #pragma unroll
    for (int ks = 0; ks < 2; ks++) {
      bf16x8 af[4], bfr[4];
      #pragma unroll
      for (int m = 0; m < 4; m++) {
        const int row = wr * 64 + m * 16 + frow;
        af[m] = *(const bf16x8*)(XIT + row * 64 + (((ks * 4 + fs) ^ (row & 7)) << 3));
      }
      #pragma unroll
      for (int n = 0; n < 4; n++) {
        const int row = wc * 64 + n * 16 + frow;
        bfr[n] = *(const bf16x8*)(XJ[cur] + row * 64 + (((ks * 4 + fs) ^ (row & 7)) << 3));
      }
      #pragma unroll
      for (int m = 0; m < 4; m++)
        #pragma unroll
        for (int n = 0; n < 4; n++)
          sacc[m][n] = __builtin_amdgcn_mfma_f32_16x16x32_bf16(af[m], bfr[n], sacc[m][n], 0, 0, 0);
    }
    __syncthreads();                 // rzs visible; PT free (prev G-gemm done)
    #pragma unroll
    for (int m = 0; m < 4; m++)
      #pragma unroll
      for (int jj = 0; jj < 4; jj++) {
        const int row = wr * 64 + m * 16 + (lane >> 4) * 4 + jj;
        const float rv = uts[row];
        #pragma unroll
        for (int n = 0; n < 4; n++) {
          const int col = wc * 64 + n * 16 + (lane & 15);
          const float p = __expf((sacc[m][n][jj] + rv) * 0.03952847075210474f) * rzs[col];
          PT[row * 128 + (((col >> 3) ^ (row & 7)) << 3) + (col & 7)] = f2bf(p);
        }
      }
    asm volatile("s_waitcnt vmcnt(0)" ::: "memory");   // XB(j), XJ[next] landed
    __syncthreads();                 // P visible
    // G-gemm: gacc += P @ XB^T-view (wave rows w*32..+32, cols 0..79, K=128)
    #pragma unroll
    for (int ks = 0; ks < 4; ks++) {
      bf16x8 af2[2], bfr2[5];
      #pragma unroll
      for (int m = 0; m < 2; m++) {
        const int row = w * 32 + m * 16 + frow;
        af2[m] = *(const bf16x8*)(PT + row * 128 + (((ks * 4 + fs) ^ (row & 7)) << 3));
      }
      #pragma unroll
      for (int n = 0; n < 5; n++) {
        const int rc = n * 16 + frow;
        bfr2[n] = *(const bf16x8*)(XB + rc * 128 + (((ks * 4 + fs) ^ (rc & 7)) << 3));
      }
      #pragma unroll
      for (int m = 0; m < 2; m++)
        #pragma unroll
        for (int n = 0; n < 5; n++)
          gacc[m][n] = __builtin_amdgcn_mfma_f32_16x16x32_bf16(af2[m], bfr2[n], gacc[m][n], 0, 0, 0);
    }
    __syncthreads();                 // all P/XB reads done before overwrite
    cur ^= 1;
  }
  // stage G-tile [128][80] in PT (dead), then coalesced stores
  #pragma unroll
  for (int m = 0; m < 2; m++)
    #pragma unroll
    for (int n = 0; n < 5; n++)
      #pragma unroll
      for (int jj = 0; jj < 4; jj++) {
        const int row = w * 32 + m * 16 + (lane >> 4) * 4 + jj;
        const int col = n * 16 + (lane & 15);
        PT[row * 80 + col] = f2bf(gacc[m][n][jj]);
      }
  __syncthreads();
  #pragma unroll
  for (int it = 0; it < 5; ++it) {
    const int task = it * 256 + tid;
    const int row = task / 10, ch = task % 10;
    bf16x8 v = *(const bf16x8*)(PT + row * 80 + ch * 8);
    *(bf16x8*)(G + (long)(i0 + row) * 320 + h * 80 + ch * 8) = v;
  }
}

// ---------------------------------------------------------------------------
// out[b][c][s] = G @ MxT^T + bo + x  (f32, fused residual, coalesced stores)
__global__ __launch_bounds__(256) void k_out(
    const u16* __restrict__ G, const u16* __restrict__ MxT,
    const float* __restrict__ bo, const float* __restrict__ x, float* __restrict__ out)
{
  __shared__ __align__(16) u16 SH[2 * 128 * 64 + 2 * 64 * 64];
  u16* As = SH; u16* Bs = SH + 2 * 128 * 64;
  f32x4 acc[2][4];
  gemm_nt<128, 64, 64, 4, 1, 2, 4>(G, MxT, 320, 320, 320,
                                   blockIdx.x * 128, 0, acc, As, Bs);
  const int lane = threadIdx.x & 63;
  const int wr = threadIdx.x >> 6;
  float* etf = (float*)SH;   // [64][132] f32
  __syncthreads();
  #pragma unroll
  for (int m = 0; m < 2; m++)
    #pragma unroll
    for (int n = 0; n < 4; n++)
      #pragma unroll
      for (int j = 0; j < 4; j++) {
        const int sl = wr * 32 + m * 16 + (lane >> 4) * 4 + j;
        const int c  = n * 16 + (lane & 15);
        etf[c * 132 + sl] = acc[m][n][j];
      }
  __syncthreads();
  const int b = blockIdx.x >> 3, s0 = (blockIdx.x & 7) * 128;
  #pragma unroll
  for (int it = 0; it < 8; ++it) {
    const int task = it * 256 + threadIdx.x;
    const int c = task >> 5, q = (task & 31) * 4;
    const float bias = bo[c];
    f32x4 v = *(const f32x4*)(etf + c * 132 + q);
    const long xi = ((long)(b * 64 + c) << 10) + s0 + q;
    const f32x4 xv = *(const f32x4*)(x + xi);
    #pragma unroll
    for (int e = 0; e < 4; e++) v[e] += bias + xv[e];
    *(f32x4*)(out + xi) = v;
  }
}

// ---------------------------------------------------------------------------
extern "C" void kernel_launch(void* const* d_in, const int* in_sizes, int n_in,
                              void* d_out, int out_size, void* d_ws, size_t ws_size,
                              hipStream_t stream)
{
  (void)in_sizes; (void)n_in; (void)out_size; (void)ws_size;
  const float* x  = (const float*)d_in[0];
  // d_in[1] = t (unused)
  const float* Wp = (const float*)d_in[2];
  const float* bp = (const float*)d_in[3];
  const float* Wo = (const float*)d_in[4];
  const float* bo = (const float*)d_in[5];
  float* out = (float*)d_out;

  char* w8 = (char*)d_ws;
  u16*   xt   = (u16*)(w8 + 0L);          // [8192][64] bf16, 1 MB
  u16*   xb   = (u16*)(w8 + 1048576L);    // [8][80][1024] bf16
  u16*   Wot  = (u16*)(w8 + 2359296L);    // [64][2560] bf16
  u16*   Wpb  = (u16*)(w8 + 2686976L);    // [64][7680] bf16
  u16*   Ahat = (u16*)(w8 + 3670016L);    // [4][64][64] bf16
  u16*   MxT  = (u16*)(w8 + 3702784L);    // [64][320] bf16
  float* uh   = (float*)(w8 + 3743744L);  // [4][64]
  float* Z    = (float*)(w8 + 3744768L);  // [32][1024] f32
  u16*   G    = (u16*)(w8 + 3875840L);    // [8192][320] bf16, 5 MB

  k_misc<<<793, 256, 0, stream>>>(x, Wp, Wo, bp, xt, Wot, Wpb, xb, uh, MxT);
  k_prep<<<8,   256, 0, stream>>>(Wpb, Wot, Ahat, MxT);
  k_qkz <<<256, 256, 0, stream>>>(xt, Ahat, uh, Z);
  k_G   <<<256, 256, 0, stream>>>(xt, xb, Ahat, uh, Z, G);
  k_out <<<64,  256, 0, stream>>>(G, MxT, bo, x, out);
}

// Round 11
// 76.224 us; speedup vs baseline: 1.2260x; 1.2260x over previous
//
#include <hip/hip_runtime.h>
#include <hip/hip_bf16.h>
#include <stdint.h>

typedef unsigned short u16;
typedef __attribute__((ext_vector_type(4))) float f32x4;
typedef __attribute__((ext_vector_type(8))) short bf16x8;

#define DEV __device__ __forceinline__

DEV float bf2f(u16 b){ unsigned u = ((unsigned)b) << 16; return __builtin_bit_cast(float, u); }
DEV u16 f2bf(float f){
  unsigned u = __builtin_bit_cast(unsigned, f);
  u += 0x7FFFu + ((u >> 16) & 1u);
  return (u16)(u >> 16);
}

// XCD-aware block swizzle (T1). Requires nwg % 8 == 0.
DEV int xcd_swz(int nwg){
  const int bid = (int)blockIdx.x;
  return (bid & 7) * (nwg >> 3) + (bid >> 3);
}

DEV void gld16(const u16* src, u16* dst){
  __builtin_amdgcn_global_load_lds(
      (const __attribute__((address_space(1))) void*)src,
      (__attribute__((address_space(3))) void*)dst, 16, 0, 0);
}

// stage a 128x64 bf16 tile (row-major lda=64) into LDS, linear dest +
// source-slot XOR pre-swizzle (slots of 8 u16, XOR row&7)
template<int NTH>
DEV void stage_x64(const u16* srcbase, u16* dst, int tid){
  #pragma unroll
  for (int q = 0; q < 16384 / (NTH * 16); q++) {
    const int boff = q * NTH * 16 + tid * 16;
    const int row = boff >> 7, slot = (boff & 127) >> 4;
    const int kk = (slot ^ (row & 7)) << 3;
    gld16(srcbase + (long)row * 64 + kk, dst + (boff >> 1));
  }
}

// 64x64-tile transpose helper: dst[c][r] = src[r][c] (f32 -> bf16)
DEV void tr_tile(float (*tile)[65], const float* src, u16* dst,
                 int R, int C, int r0, int c0)
{
  const int t = threadIdx.x;
  const int rr = t >> 2, cc = (t & 3) * 16;
  const float* sp = src + (long)(r0 + rr) * C + (c0 + cc);
  #pragma unroll
  for (int q = 0; q < 16; q++) tile[rr][cc + q] = sp[q];
  __syncthreads();
  u16* dp = dst + (long)(c0 + rr) * R + (r0 + cc);
  #pragma unroll
  for (int q = 0; q < 16; q++) dp[q] = f2bf(tile[cc + q][rr]);
}

// ---------------------------------------------------------------------------
// Consolidated prep: Wp->bf16 | x^T | Wo^T | uh = Wq^T bk | x->xb (+ones)
__global__ __launch_bounds__(256) void k_misc(
    const float* __restrict__ x, const float* __restrict__ Wp,
    const float* __restrict__ Wo, const float* __restrict__ bp,
    u16* __restrict__ xt, u16* __restrict__ Wot, u16* __restrict__ Wpb,
    u16* __restrict__ xb, float* __restrict__ uh)
{
  __shared__ float tile[64][65];
  const int q = blockIdx.x;
  if (q < 240) {                      // Wp -> Wpb (bf16 flat cast)
    const long i = (long)q * 256 + threadIdx.x;
    const f32x4 a = *(const f32x4*)(Wp + i * 8);
    const f32x4 b = *(const f32x4*)(Wp + i * 8 + 4);
    bf16x8 r;
    #pragma unroll
    for (int e = 0; e < 4; e++){ r[e] = (short)f2bf(a[e]); r[e+4] = (short)f2bf(b[e]); }
    *(bf16x8*)(Wpb + i * 8) = r;
  } else if (q < 368) {               // x -> xt (per-batch 64x1024 transpose)
    const int p = q - 240, c0 = (p & 15) * 64, b = p >> 4;
    tr_tile(tile, x + (long)b * 65536, xt + (long)b * 65536, 64, 1024, 0, c0);
  } else if (q < 408) {               // Wo -> Wot
    const int p = q - 368;
    tr_tile(tile, Wo, Wot, 2560, 64, p * 64, 0);
  } else if (q < 472) {               // uh[h][c] = Wq[c] . bk (one wave each)
    const int p = q - 408;
    const int wv = threadIdx.x >> 6, lane = threadIdx.x & 63;
    const int idx = p * 4 + wv;       // 0..255
    const int h = idx >> 6, c = idx & 63;
    const int qb = h * 1920, kb = qb + 640;
    const float* wrow = Wp + (long)c * 7680 + qb;
    float s = 0.f;
    #pragma unroll
    for (int d0 = 0; d0 < 640; d0 += 64)
      s += wrow[d0 + lane] * bp[kb + d0 + lane];
    #pragma unroll
    for (int off = 32; off; off >>= 1) s += __shfl_down(s, off);
    if (lane == 0) uh[idx] = s;
  } else {                            // x -> xb [8][80][1024]; row64=1, 65-79=0
    const int ch = (q - 472) * 256 + threadIdx.x;     // 81920 chunks of 8
    const int b = ch / 10240, rem = ch % 10240;
    const int row = rem >> 7, j8 = rem & 127;
    bf16x8 r;
    if (row < 64) {
      const float* sp = x + ((long)b * 64 + row) * 1024 + j8 * 8;
      const f32x4 a = *(const f32x4*)sp;
      const f32x4 bb = *(const f32x4*)(sp + 4);
      #pragma unroll
      for (int e = 0; e < 4; e++){ r[e] = (short)f2bf(a[e]); r[e+4] = (short)f2bf(bb[e]); }
    } else if (row == 64) {
      #pragma unroll
      for (int e = 0; e < 8; e++) r[e] = (short)0x3F80;   // 1.0 bf16
    } else {
      #pragma unroll
      for (int e = 0; e < 8; e++) r[e] = 0;
    }
    *(bf16x8*)(xb + ((long)b * 80 + row) * 1024 + j8 * 8) = r;
  }
}

// nh row of MxT: MxT[c'][h*80+64] = sum_d bv[d]*Wo[h*640+d][c']; cols 65-79 = 0
// 64 blocks x 4 waves; wave-parallel over d (coalesced Wot reads).
__global__ __launch_bounds__(256) void k_nh(
    const u16* __restrict__ Wot, const float* __restrict__ bp,
    u16* __restrict__ MxT)
{
  const int wv = threadIdx.x >> 6, lane = threadIdx.x & 63;
  const int idx = blockIdx.x * 4 + wv;   // 0..255
  const int h = idx >> 6, cp = idx & 63;
  const u16* wr_ = Wot + (long)cp * 2560 + h * 640;
  const float* bv = bp + h * 1920 + 1280;
  float s = 0.f;
  #pragma unroll
  for (int d0 = 0; d0 < 640; d0 += 64)
    s += bf2f(wr_[d0 + lane]) * bv[d0 + lane];
  #pragma unroll
  for (int off = 32; off; off >>= 1) s += __shfl_down(s, off);
  if (lane == 0) MxT[cp * 320 + h * 80 + 64] = f2bf(s);
  if (lane >= 1 && lane < 16) MxT[cp * 320 + h * 80 + 64 + lane] = 0;
}

// ---------------------------------------------------------------------------
// NT GEMM tile core, 2-phase double-buffered + both-sides XOR swizzle.
template<int BM, int BN, int BK, int WR, int WC, int MF, int NF>
DEV void gemm_nt(const u16* __restrict__ A, const u16* __restrict__ B,
                 int K, long lda, long ldb, int arow0, int brow0,
                 f32x4 (&acc)[MF][NF], u16* As, u16* Bs)
{
  const int tid  = threadIdx.x;
  const int lane = tid & 63;
  const int w    = tid >> 6;
  const int wr   = w / WC, wc = w % WC;
  constexpr int NT   = WR * WC * 64;
  constexpr int AISS = (BM * BK * 2) / (NT * 16);
  constexpr int BISS = (BN * BK * 2) / (NT * 16);
  constexpr int ABUF = BM * BK;
  constexpr int BBUF = BN * BK;

  #pragma unroll
  for (int m = 0; m < MF; m++)
    #pragma unroll
    for (int n = 0; n < NF; n++) acc[m][n] = f32x4{0.f, 0.f, 0.f, 0.f};

  const int frow = lane & 15;
  const int fs   = lane >> 4;

  auto stage = [&](int buf, int kt) {
    #pragma unroll
    for (int q = 0; q < AISS; q++) {
      const int boff = q * NT * 16 + tid * 16;
      const int row  = boff / (BK * 2);
      const int slot = (boff % (BK * 2)) >> 4;
      const int kk   = ((slot ^ (row & 7)) << 3);
      gld16(A + (long)(arow0 + row) * lda + kt + kk, As + buf * ABUF + (boff >> 1));
    }
    #pragma unroll
    for (int q = 0; q < BISS; q++) {
      const int boff = q * NT * 16 + tid * 16;
      const int row  = boff / (BK * 2);
      const int slot = (boff % (BK * 2)) >> 4;
      const int kk   = ((slot ^ (row & 7)) << 3);
      gld16(B + (long)(brow0 + row) * ldb + kt + kk, Bs + buf * BBUF + (boff >> 1));
    }
  };

  auto compute = [&](int buf) {
    __builtin_amdgcn_s_setprio(1);
    #pragma unroll
    for (int ks = 0; ks < BK / 32; ++ks) {
      bf16x8 af[MF], bfr[NF];
      #pragma unroll
      for (int m = 0; m < MF; m++) {
        const int row  = wr * (MF * 16) + m * 16 + frow;
        const int slot = (ks * 4 + fs) ^ (row & 7);
        af[m] = *(const bf16x8*)(As + buf * ABUF + row * BK + slot * 8);
      }
      #pragma unroll
      for (int n = 0; n < NF; n++) {
        const int row  = wc * (NF * 16) + n * 16 + frow;
        const int slot = (ks * 4 + fs) ^ (row & 7);
        bfr[n] = *(const bf16x8*)(Bs + buf * BBUF + row * BK + slot * 8);
      }
      #pragma unroll
      for (int m = 0; m < MF; m++)
        #pragma unroll
        for (int n = 0; n < NF; n++)
          acc[m][n] = __builtin_amdgcn_mfma_f32_16x16x32_bf16(af[m], bfr[n], acc[m][n], 0, 0, 0);
    }
    __builtin_amdgcn_s_setprio(0);
  };

  stage(0, 0);
  asm volatile("s_waitcnt vmcnt(0)" ::: "memory");
  __syncthreads();
  int cur = 0;
  for (int kt = BK; kt < K; kt += BK) {
    stage(cur ^ 1, kt);
    compute(cur);
    asm volatile("s_waitcnt vmcnt(0)" ::: "memory");
    __syncthreads();
    cur ^= 1;
  }
  compute(cur);
}

// Per-wave epilogue: stage wave tile into LDS swizzled, coalesced bf16x8 stores
template<int MF, int NF, typename FV, typename FS>
DEV void epi_u16(u16* SH, FV&& fval, FS&& fstore)
{
  constexpr int RC = MF * 16, CC = NF * 16, CPR = NF * 2;
  const int lane = threadIdx.x & 63;
  const int w = threadIdx.x >> 6;
  u16* et = SH + w * (RC * CC);
  __syncthreads();
  #pragma unroll
  for (int m = 0; m < MF; m++)
    #pragma unroll
    for (int n = 0; n < NF; n++)
      #pragma unroll
      for (int j = 0; j < 4; j++) {
        const int row = m * 16 + (lane >> 4) * 4 + j;
        const int col = n * 16 + (lane & 15);
        et[row * CC + (((col >> 3) ^ row) & (CPR - 1)) * 8 + (col & 7)] =
            f2bf(fval(m, n, j, row, col));
      }
  constexpr int RPI = 64 / CPR;
  #pragma unroll
  for (int it = 0; it < RC / RPI; ++it) {
    const int row = it * RPI + lane / CPR;
    const int ch  = lane % CPR;
    bf16x8 v = *(const bf16x8*)(et + row * CC + ((ch ^ row) & (CPR - 1)) * 8);
    fstore(row, ch * 8, v);
  }
}

// ---------------------------------------------------------------------------
// k_prep: blocks 0-3: Ahat[h] = Wk_h @ Wq_h^T; blocks 4-7: MxT = (Wv_h Wo_h)^T
__global__ __launch_bounds__(256) void k_prep(
    const u16* __restrict__ Wpb, const u16* __restrict__ Wot,
    u16* __restrict__ Ahat, u16* __restrict__ MxT)
{
  __shared__ __align__(16) u16 SH[4 * 64 * 64];
  u16* As = SH; u16* Bs = SH + 2 * 64 * 64;
  const int q = blockIdx.x;
  const int w = threadIdx.x >> 6;
  const int wr = w >> 1, wc = w & 1;
  f32x4 acc[2][2];
  if (q < 4) {
    const int h = q;
    gemm_nt<64, 64, 64, 2, 2, 2, 2>(Wpb + h * 1920 + 640, Wpb + h * 1920, 640,
                                    7680, 7680, 0, 0, acc, As, Bs);
    u16* dst = Ahat + h * 4096;
    epi_u16<2, 2>(SH,
      [&](int m, int n, int j, int row, int col){ return acc[m][n][j]; },
      [&](int row, int c0, bf16x8 v){
        *(bf16x8*)(dst + (wr * 32 + row) * 64 + wc * 32 + c0) = v; });
  } else {
    const int h = q - 4;
    gemm_nt<64, 64, 64, 2, 2, 2, 2>(Wot + h * 640, Wpb + h * 1920 + 1280, 640,
                                    2560, 7680, 0, 0, acc, As, Bs);
    epi_u16<2, 2>(SH,
      [&](int m, int n, int j, int row, int col){ return acc[m][n][j]; },
      [&](int row, int c0, bf16x8 v){
        *(bf16x8*)(MxT + (long)(wr * 32 + row) * 320 + h * 80 + wc * 32 + c0) = v; });
  }
}

// ---------------------------------------------------------------------------
// Pass 1: Z[bh][j] = sum_i exp(SCALE*(T_i.x_j + ut_i)). No P store.
// grid 256 = (bh, tj); per block loop over 8 i-tiles, T recomputed in LDS.
__global__ __launch_bounds__(256) void k_qkz(
    const u16* __restrict__ xt, const u16* __restrict__ Ahat,
    const float* __restrict__ uh, float* __restrict__ Z)
{
  __shared__ __align__(16) u16 XI[2][8192];
  __shared__ __align__(16) u16 AH[4096];
  __shared__ __align__(16) u16 XJ[8192];
  __shared__ __align__(16) u16 TT[8192];
  __shared__ float uts[128];
  __shared__ float uhl[64];
  __shared__ float Zs[2][128];
  const int tid = threadIdx.x, lane = tid & 63, w = tid >> 6;
  const int frow = lane & 15, fs = lane >> 4;
  const int wr = w >> 1, wc = w & 1;
  const int id = xcd_swz(256);
  const int bh = id >> 3, tj = id & 7;
  const int b = bh >> 2, h = bh & 3;
  const int j0 = b * 1024 + tj * 128;

  #pragma unroll
  for (int q = 0; q < 2; q++) {       // AH
    const int boff = q * 4096 + tid * 16;
    const int row = boff >> 7, slot = (boff & 127) >> 4;
    const int kk = (slot ^ (row & 7)) << 3;
    gld16(Ahat + h * 4096 + row * 64 + kk, AH + (boff >> 1));
  }
  stage_x64<256>(xt + (long)j0 * 64, XJ, tid);
  stage_x64<256>(xt + (long)(b * 1024) * 64, XI[0], tid);
  if (tid < 64) uhl[tid] = uh[h * 64 + tid];
  asm volatile("s_waitcnt vmcnt(0)" ::: "memory");
  __syncthreads();

  float csum[4] = {0.f, 0.f, 0.f, 0.f};
  int cur = 0;
  for (int it = 0; it < 8; ++it) {
    if (it < 7) stage_x64<256>(xt + (long)(b * 1024 + (it + 1) * 128) * 64, XI[cur ^ 1], tid);
    // T-gemm: T = XI[cur] @ AH^T (wave 64x32)
    f32x4 acc1[4][2];
    #pragma unroll
    for (int m = 0; m < 4; m++)
      #pragma unroll
      for (int n = 0; n < 2; n++) acc1[m][n] = f32x4{0.f, 0.f, 0.f, 0.f};
    #pragma unroll
    for (int ks = 0; ks < 2; ks++) {
      bf16x8 af[4], bfr[2];
      #pragma unroll
      for (int m = 0; m < 4; m++) {
        const int row = wr * 64 + m * 16 + frow;
        af[m] = *(const bf16x8*)(XI[cur] + row * 64 + (((ks * 4 + fs) ^ (row & 7)) << 3));
      }
      #pragma unroll
      for (int n = 0; n < 2; n++) {
        const int row = wc * 32 + n * 16 + frow;
        bfr[n] = *(const bf16x8*)(AH + row * 64 + (((ks * 4 + fs) ^ (row & 7)) << 3));
      }
      #pragma unroll
      for (int m = 0; m < 4; m++)
        #pragma unroll
        for (int n = 0; n < 2; n++)
          acc1[m][n] = __builtin_amdgcn_mfma_f32_16x16x32_bf16(af[m], bfr[n], acc1[m][n], 0, 0, 0);
    }
    float su = 0.f;
    if (tid < 128) {
      #pragma unroll
      for (int s = 0; s < 8; s++) {
        bf16x8 v = *(const bf16x8*)(XI[cur] + tid * 64 + ((s ^ (tid & 7)) << 3));
        #pragma unroll
        for (int e = 0; e < 8; e++) su += bf2f((u16)v[e]) * uhl[s * 8 + e];
      }
    }
    __syncthreads();                 // prev TT/uts reads done
    if (tid < 128) uts[tid] = su;
    #pragma unroll
    for (int m = 0; m < 4; m++)
      #pragma unroll
      for (int n = 0; n < 2; n++)
        #pragma unroll
        for (int j = 0; j < 4; j++) {
          const int row = wr * 64 + m * 16 + (lane >> 4) * 4 + j;
          const int col = wc * 32 + n * 16 + (lane & 15);
          TT[row * 64 + (((col >> 3) ^ (row & 7)) << 3) + (col & 7)] = f2bf(acc1[m][n][j]);
        }
    asm volatile("s_waitcnt vmcnt(0)" ::: "memory");
    __syncthreads();                 // TT/uts visible; XI[cur^1] landed
    // S-gemm + exp + csum
    f32x4 sacc[4][4];
    #pragma unroll
    for (int m = 0; m < 4; m++)
      #pragma unroll
      for (int n = 0; n < 4; n++) sacc[m][n] = f32x4{0.f, 0.f, 0.f, 0.f};
    #pragma unroll
    for (int ks = 0; ks < 2; ks++) {
      bf16x8 af[4], bfr[4];
      #pragma unroll
      for (int m = 0; m < 4; m++) {
        const int row = wr * 64 + m * 16 + frow;
        af[m] = *(const bf16x8*)(TT + row * 64 + (((ks * 4 + fs) ^ (row & 7)) << 3));
      }
      #pragma unroll
      for (int n = 0; n < 4; n++) {
        const int row = wc * 64 + n * 16 + frow;
        bfr[n] = *(const bf16x8*)(XJ + row * 64 + (((ks * 4 + fs) ^ (row & 7)) << 3));
      }
      #pragma unroll
      for (int m = 0; m < 4; m++)
        #pragma unroll
        for (int n = 0; n < 4; n++)
          sacc[m][n] = __builtin_amdgcn_mfma_f32_16x16x32_bf16(af[m], bfr[n], sacc[m][n], 0, 0, 0);
    }
    #pragma unroll
    for (int m = 0; m < 4; m++)
      #pragma unroll
      for (int j = 0; j < 4; j++) {
        const float rv = uts[wr * 64 + m * 16 + (lane >> 4) * 4 + j];
        #pragma unroll
        for (int n = 0; n < 4; n++)
          csum[n] += __expf((sacc[m][n][j] + rv) * 0.03952847075210474f);
      }
    cur ^= 1;
  }
  #pragma unroll
  for (int n = 0; n < 4; n++) {
    csum[n] += __shfl_xor(csum[n], 16);
    csum[n] += __shfl_xor(csum[n], 32);
  }
  if ((lane >> 4) == 0) {
    #pragma unroll
    for (int n = 0; n < 4; n++) Zs[wr][wc * 64 + n * 16 + lane] = csum[n];
  }
  __syncthreads();
  if (tid < 128) Z[(long)bh * 1024 + tj * 128 + tid] = Zs[0][tid] + Zs[1][tid];
}

// ---------------------------------------------------------------------------
// Pass 2: G[b*1024+i][h*80+c] = sum_j (exp(..)/Z[j]) * xb[b][c][j]
// 4 waves (256 threads), grid 256 = (bh, ti).
__global__ __launch_bounds__(256) void k_G(
    const u16* __restrict__ xt, const u16* __restrict__ xb,
    const u16* __restrict__ Ahat, const float* __restrict__ uh,
    const float* __restrict__ Z, u16* __restrict__ G)
{
  __shared__ __align__(16) u16 XIT[8192];    // XI, then T
  __shared__ __align__(16) u16 AH[4096];
  __shared__ __align__(16) u16 XJ[2][8192];
  __shared__ __align__(16) u16 XB[10240];    // [80][128]
  __shared__ __align__(16) u16 PT[16384];    // P-tile [128][128]; then G staging
  __shared__ float uts[128];
  __shared__ float uhl[64];
  __shared__ float rzs[128];
  const int tid = threadIdx.x, lane = tid & 63, w = tid >> 6;
  const int frow = lane & 15, fs = lane >> 4;
  const int wr = w >> 1, wc = w & 1;
  const int id = xcd_swz(256);
  const int bh = id >> 3, ti = id & 7;
  const int b = bh >> 2, h = bh & 3;
  const int i0 = b * 1024 + ti * 128;

  #pragma unroll
  for (int q = 0; q < 2; q++) {       // AH
    const int boff = q * 4096 + tid * 16;
    const int row = boff >> 7, slot = (boff & 127) >> 4;
    const int kk = (slot ^ (row & 7)) << 3;
    gld16(Ahat + h * 4096 + row * 64 + kk, AH + (boff >> 1));
  }
  stage_x64<256>(xt + (long)i0 * 64, XIT, tid);
  stage_x64<256>(xt + (long)(b * 1024) * 64, XJ[0], tid);
  if (tid < 64) uhl[tid] = uh[h * 64 + tid];
  asm volatile("s_waitcnt vmcnt(0)" ::: "memory");
  __syncthreads();

  // T-gemm + ut
  f32x4 acc1[4][2];
  #pragma unroll
  for (int m = 0; m < 4; m++)
    #pragma unroll
    for (int n = 0; n < 2; n++) acc1[m][n] = f32x4{0.f, 0.f, 0.f, 0.f};
  #pragma unroll
  for (int ks = 0; ks < 2; ks++) {
    bf16x8 af[4], bfr[2];
    #pragma unroll
    for (int m = 0; m < 4; m++) {
      const int row = wr * 64 + m * 16 + frow;
      af[m] = *(const bf16x8*)(XIT + row * 64 + (((ks * 4 + fs) ^ (row & 7)) << 3));
    }
    #pragma unroll
    for (int n = 0; n < 2; n++) {
      const int row = wc * 32 + n * 16 + frow;
      bfr[n] = *(const bf16x8*)(AH + row * 64 + (((ks * 4 + fs) ^ (row & 7)) << 3));
    }
    #pragma unroll
    for (int m = 0; m < 4; m++)
      #pragma unroll
      for (int n = 0; n < 2; n++)
        acc1[m][n] = __builtin_amdgcn_mfma_f32_16x16x32_bf16(af[m], bfr[n], acc1[m][n], 0, 0, 0);
  }
  float su = 0.f;
  if (tid < 128) {
    #pragma unroll
    for (int s = 0; s < 8; s++) {
      bf16x8 v = *(const bf16x8*)(XIT + tid * 64 + ((s ^ (tid & 7)) << 3));
      #pragma unroll
      for (int e = 0; e < 8; e++) su += bf2f((u16)v[e]) * uhl[s * 8 + e];
    }
  }
  __syncthreads();                   // all XIT reads done
  if (tid < 128) uts[tid] = su;
  #pragma unroll
  for (int m = 0; m < 4; m++)        // write T over XIT
    #pragma unroll
    for (int n = 0; n < 2; n++)
      #pragma unroll
      for (int j = 0; j < 4; j++) {
        const int row = wr * 64 + m * 16 + (lane >> 4) * 4 + j;
        const int col = wc * 32 + n * 16 + (lane & 15);
        XIT[row * 64 + (((col >> 3) ^ (row & 7)) << 3) + (col & 7)] = f2bf(acc1[m][n][j]);
      }
  __syncthreads();                   // T/uts visible

  f32x4 gacc[2][5];
  #pragma unroll
  for (int m = 0; m < 2; m++)
    #pragma unroll
    for (int n = 0; n < 5; n++) gacc[m][n] = f32x4{0.f, 0.f, 0.f, 0.f};
  int cur = 0;
  for (int j = 0; j < 8; ++j) {
    // stage XB(j): [80][128] from xb[b][c][j*128..]
    #pragma unroll
    for (int q = 0; q < 5; q++) {
      const int boff = q * 4096 + tid * 16;
      const int c = boff >> 8, sl = (boff & 255) >> 4;
      const int kk = (sl ^ (c & 7)) << 3;
      gld16(xb + ((long)b * 80 + c) * 1024 + j * 128 + kk, XB + (boff >> 1));
    }
    if (j < 7) stage_x64<256>(xt + (long)(b * 1024 + (j + 1) * 128) * 64, XJ[cur ^ 1], tid);
    if (tid < 128) rzs[tid] = 1.0f / Z[(long)bh * 1024 + j * 128 + tid];
    // S-gemm: S = T @ XJ[cur]^T (wave 64x64)
    f32x4 sacc[4][4];
    #pragma unroll
    for (int m = 0; m < 4; m++)
      #pragma unroll
      for (int n = 0; n < 4; n++) sacc[m][n] = f32x4{0.f, 0.f, 0.f, 0.f};
    #pragma unroll
    for (int ks = 0; ks < 2; ks++) {
      bf16x8 af[4], bfr[4];
      #pragma unroll
      for (int m = 0; m < 4; m++) {
        const int row = wr * 64 + m * 16 + frow;
        af[m] = *(const bf16x8*)(XIT + row * 64 + (((ks * 4 + fs) ^ (row & 7)) << 3));
      }
      #pragma unroll
      for (int n = 0; n < 4; n++) {
        const int row = wc * 64 + n * 16 + frow;
        bfr[n] = *(const bf16x8*)(XJ[cur] + row * 64 + (((ks * 4 + fs) ^ (row & 7)) << 3));
      }
      #pragma unroll
      for (int m = 0; m < 4; m++)
        #pragma unroll
        for (int n = 0; n < 4; n++)
          sacc[m][n] = __builtin_amdgcn_mfma_f32_16x16x32_bf16(af[m], bfr[n], sacc[m][n], 0, 0, 0);
    }
    __syncthreads();                 // rzs visible; PT free (prev G-gemm done)
    #pragma unroll
    for (int m = 0; m < 4; m++)
      #pragma unroll
      for (int jj = 0; jj < 4; jj++) {
        const int row = wr * 64 + m * 16 + (lane >> 4) * 4 + jj;
        const float rv = uts[row];
        #pragma unroll
        for (int n = 0; n < 4; n++) {
          const int col = wc * 64 + n * 16 + (lane & 15);
          const float p = __expf((sacc[m][n][jj] + rv) * 0.03952847075210474f) * rzs[col];
          PT[row * 128 + (((col >> 3) ^ (row & 7)) << 3) + (col & 7)] = f2bf(p);
        }
      }
    asm volatile("s_waitcnt vmcnt(0)" ::: "memory");   // XB(j), XJ[next] landed
    __syncthreads();                 // P visible
    // G-gemm: gacc += P @ XB^T-view (wave rows w*32..+32, cols 0..79, K=128)
    #pragma unroll
    for (int ks = 0; ks < 4; ks++) {
      bf16x8 af2[2], bfr2[5];
      #pragma unroll
      for (int m = 0; m < 2; m++) {
        const int row = w * 32 + m * 16 + frow;
        af2[m] = *(const bf16x8*)(PT + row * 128 + (((ks * 4 + fs) ^ (row & 7)) << 3));
      }
      #pragma unroll
      for (int n = 0; n < 5; n++) {
        const int rc = n * 16 + frow;
        bfr2[n] = *(const bf16x8*)(XB + rc * 128 + (((ks * 4 + fs) ^ (rc & 7)) << 3));
      }
      #pragma unroll
      for (int m = 0; m < 2; m++)
        #pragma unroll
        for (int n = 0; n < 5; n++)
          gacc[m][n] = __builtin_amdgcn_mfma_f32_16x16x32_bf16(af2[m], bfr2[n], gacc[m][n], 0, 0, 0);
    }
    __syncthreads();                 // all P/XB reads done before overwrite
    cur ^= 1;
  }
  // stage G-tile [128][80] in PT (dead), then coalesced stores
  #pragma unroll
  for (int m = 0; m < 2; m++)
    #pragma unroll
    for (int n = 0; n < 5; n++)
      #pragma unroll
      for (int jj = 0; jj < 4; jj++) {
        const int row = w * 32 + m * 16 + (lane >> 4) * 4 + jj;
        const int col = n * 16 + (lane & 15);
        PT[row * 80 + col] = f2bf(gacc[m][n][jj]);
      }
  __syncthreads();
  #pragma unroll
  for (int it = 0; it < 5; ++it) {
    const int task = it * 256 + tid;
    const int row = task / 10, ch = task % 10;
    bf16x8 v = *(const bf16x8*)(PT + row * 80 + ch * 8);
    *(bf16x8*)(G + (long)(i0 + row) * 320 + h * 80 + ch * 8) = v;
  }
}

// ---------------------------------------------------------------------------
// out[b][c][s] = G @ MxT^T + bo + x  (f32, fused residual, coalesced stores)
// BM=64 -> 128 blocks (2x CU coverage vs BM=128; this kernel is HBM-bound).
__global__ __launch_bounds__(256) void k_out(
    const u16* __restrict__ G, const u16* __restrict__ MxT,
    const float* __restrict__ bo, const float* __restrict__ x, float* __restrict__ out)
{
  __shared__ __align__(16) u16 SH[4 * 64 * 64];   // As+Bs 32 KB; reused as etf
  u16* As = SH; u16* Bs = SH + 2 * 64 * 64;
  f32x4 acc[2][2];
  gemm_nt<64, 64, 64, 2, 2, 2, 2>(G, MxT, 320, 320, 320,
                                  blockIdx.x * 64, 0, acc, As, Bs);
  const int lane = threadIdx.x & 63;
  const int w = threadIdx.x >> 6;
  const int wr = w >> 1, wc = w & 1;
  float* etf = (float*)SH;   // [64 c][68] f32 = 17408 B
  __syncthreads();
  #pragma unroll
  for (int m = 0; m < 2; m++)
    #pragma unroll
    for (int n = 0; n < 2; n++)
      #pragma unroll
      for (int j = 0; j < 4; j++) {
        const int sl = wr * 32 + m * 16 + (lane >> 4) * 4 + j;   // s-local
        const int c  = wc * 32 + n * 16 + (lane & 15);           // channel
        etf[c * 68 + sl] = acc[m][n][j];
      }
  __syncthreads();
  const int b = blockIdx.x >> 4, s0 = (blockIdx.x & 15) * 64;
  #pragma unroll
  for (int it = 0; it < 4; ++it) {
    const int task = it * 256 + threadIdx.x;   // 1024 tasks: 64 c x 16 chunks
    const int c = task >> 4, q = (task & 15) * 4;
    const float bias = bo[c];
    f32x4 v = *(const f32x4*)(etf + c * 68 + q);
    const long xi = ((long)(b * 64 + c) << 10) + s0 + q;
    const f32x4 xv = *(const f32x4*)(x + xi);
    #pragma unroll
    for (int e = 0; e < 4; e++) v[e] += bias + xv[e];
    *(f32x4*)(out + xi) = v;
  }
}

// ---------------------------------------------------------------------------
extern "C" void kernel_launch(void* const* d_in, const int* in_sizes, int n_in,
                              void* d_out, int out_size, void* d_ws, size_t ws_size,
                              hipStream_t stream)
{
  (void)in_sizes; (void)n_in; (void)out_size; (void)ws_size;
  const float* x  = (const float*)d_in[0];
  // d_in[1] = t (unused)
  const float* Wp = (const float*)d_in[2];
  const float* bp = (const float*)d_in[3];
  const float* Wo = (const float*)d_in[4];
  const float* bo = (const float*)d_in[5];
  float* out = (float*)d_out;

  char* w8 = (char*)d_ws;
  u16*   xt   = (u16*)(w8 + 0L);          // [8192][64] bf16, 1 MB
  u16*   xb   = (u16*)(w8 + 1048576L);    // [8][80][1024] bf16
  u16*   Wot  = (u16*)(w8 + 2359296L);    // [64][2560] bf16
  u16*   Wpb  = (u16*)(w8 + 2686976L);    // [64][7680] bf16
  u16*   Ahat = (u16*)(w8 + 3670016L);    // [4][64][64] bf16
  u16*   MxT  = (u16*)(w8 + 3702784L);    // [64][320] bf16
  float* uh   = (float*)(w8 + 3743744L);  // [4][64]
  float* Z    = (float*)(w8 + 3744768L);  // [32][1024] f32
  u16*   G    = (u16*)(w8 + 3875840L);    // [8192][320] bf16, 5 MB

  k_misc<<<792, 256, 0, stream>>>(x, Wp, Wo, bp, xt, Wot, Wpb, xb, uh);
  k_nh  <<<64,  256, 0, stream>>>(Wot, bp, MxT);
  k_prep<<<8,   256, 0, stream>>>(Wpb, Wot, Ahat, MxT);
  k_qkz <<<256, 256, 0, stream>>>(xt, Ahat, uh, Z);
  k_G   <<<256, 256, 0, stream>>>(xt, xb, Ahat, uh, Z, G);
  k_out <<<128, 256, 0, stream>>>(G, MxT, bo, x, out);
}

// Round 12
// 73.950 us; speedup vs baseline: 1.2637x; 1.0307x over previous
//
#include <hip/hip_runtime.h>
#include <hip/hip_bf16.h>
#include <stdint.h>

typedef unsigned short u16;
typedef __attribute__((ext_vector_type(4))) float f32x4;
typedef __attribute__((ext_vector_type(8))) short bf16x8;

#define DEV __device__ __forceinline__

DEV float bf2f(u16 b){ unsigned u = ((unsigned)b) << 16; return __builtin_bit_cast(float, u); }
DEV u16 f2bf(float f){
  unsigned u = __builtin_bit_cast(unsigned, f);
  u += 0x7FFFu + ((u >> 16) & 1u);
  return (u16)(u >> 16);
}

// XCD-aware block swizzle (T1). Requires nwg % 8 == 0.
DEV int xcd_swz(int nwg){
  const int bid = (int)blockIdx.x;
  return (bid & 7) * (nwg >> 3) + (bid >> 3);
}

DEV void gld16(const u16* src, u16* dst){
  __builtin_amdgcn_global_load_lds(
      (const __attribute__((address_space(1))) void*)src,
      (__attribute__((address_space(3))) void*)dst, 16, 0, 0);
}

// stage a 128x64 bf16 tile (row-major lda=64) into LDS, linear dest +
// source-slot XOR pre-swizzle (slots of 8 u16, XOR row&7)
template<int NTH>
DEV void stage_x64(const u16* srcbase, u16* dst, int tid){
  #pragma unroll
  for (int q = 0; q < 16384 / (NTH * 16); q++) {
    const int boff = q * NTH * 16 + tid * 16;
    const int row = boff >> 7, slot = (boff & 127) >> 4;
    const int kk = (slot ^ (row & 7)) << 3;
    gld16(srcbase + (long)row * 64 + kk, dst + (boff >> 1));
  }
}

// 64x64-tile transpose helper: dst[c][r] = src[r][c] (f32 -> bf16)
DEV void tr_tile(float (*tile)[65], const float* src, u16* dst,
                 int R, int C, int r0, int c0)
{
  const int t = threadIdx.x;
  const int rr = t >> 2, cc = (t & 3) * 16;
  const float* sp = src + (long)(r0 + rr) * C + (c0 + cc);
  #pragma unroll
  for (int q = 0; q < 16; q++) tile[rr][cc + q] = sp[q];
  __syncthreads();
  u16* dp = dst + (long)(c0 + rr) * R + (r0 + cc);
  #pragma unroll
  for (int q = 0; q < 16; q++) dp[q] = f2bf(tile[cc + q][rr]);
}

// ---------------------------------------------------------------------------
// Consolidated prep: Wp->bf16 | x^T | Wo^T | uh = Wq^T bk | x->xb (+ones)
__global__ __launch_bounds__(256) void k_misc(
    const float* __restrict__ x, const float* __restrict__ Wp,
    const float* __restrict__ Wo, const float* __restrict__ bp,
    u16* __restrict__ xt, u16* __restrict__ Wot, u16* __restrict__ Wpb,
    u16* __restrict__ xb, float* __restrict__ uh)
{
  __shared__ float tile[64][65];
  const int q = blockIdx.x;
  if (q < 240) {                      // Wp -> Wpb (bf16 flat cast)
    const long i = (long)q * 256 + threadIdx.x;
    const f32x4 a = *(const f32x4*)(Wp + i * 8);
    const f32x4 b = *(const f32x4*)(Wp + i * 8 + 4);
    bf16x8 r;
    #pragma unroll
    for (int e = 0; e < 4; e++){ r[e] = (short)f2bf(a[e]); r[e+4] = (short)f2bf(b[e]); }
    *(bf16x8*)(Wpb + i * 8) = r;
  } else if (q < 368) {               // x -> xt (per-batch 64x1024 transpose)
    const int p = q - 240, c0 = (p & 15) * 64, b = p >> 4;
    tr_tile(tile, x + (long)b * 65536, xt + (long)b * 65536, 64, 1024, 0, c0);
  } else if (q < 408) {               // Wo -> Wot
    const int p = q - 368;
    tr_tile(tile, Wo, Wot, 2560, 64, p * 64, 0);
  } else if (q < 472) {               // uh[h][c] = Wq[c] . bk (one wave each)
    const int p = q - 408;
    const int wv = threadIdx.x >> 6, lane = threadIdx.x & 63;
    const int idx = p * 4 + wv;       // 0..255
    const int h = idx >> 6, c = idx & 63;
    const int qb = h * 1920, kb = qb + 640;
    const float* wrow = Wp + (long)c * 7680 + qb;
    float s = 0.f;
    #pragma unroll
    for (int d0 = 0; d0 < 640; d0 += 64)
      s += wrow[d0 + lane] * bp[kb + d0 + lane];
    #pragma unroll
    for (int off = 32; off; off >>= 1) s += __shfl_down(s, off);
    if (lane == 0) uh[idx] = s;
  } else {                            // x -> xb [8][80][1024]; row64=1, 65-79=0
    const int ch = (q - 472) * 256 + threadIdx.x;     // 81920 chunks of 8
    const int b = ch / 10240, rem = ch % 10240;
    const int row = rem >> 7, j8 = rem & 127;
    bf16x8 r;
    if (row < 64) {
      const float* sp = x + ((long)b * 64 + row) * 1024 + j8 * 8;
      const f32x4 a = *(const f32x4*)sp;
      const f32x4 bb = *(const f32x4*)(sp + 4);
      #pragma unroll
      for (int e = 0; e < 4; e++){ r[e] = (short)f2bf(a[e]); r[e+4] = (short)f2bf(bb[e]); }
    } else if (row == 64) {
      #pragma unroll
      for (int e = 0; e < 8; e++) r[e] = (short)0x3F80;   // 1.0 bf16
    } else {
      #pragma unroll
      for (int e = 0; e < 8; e++) r[e] = 0;
    }
    *(bf16x8*)(xb + ((long)b * 80 + row) * 1024 + j8 * 8) = r;
  }
}

// ---------------------------------------------------------------------------
// NT GEMM tile core, 2-phase double-buffered + both-sides XOR swizzle.
template<int BM, int BN, int BK, int WR, int WC, int MF, int NF>
DEV void gemm_nt(const u16* __restrict__ A, const u16* __restrict__ B,
                 int K, long lda, long ldb, int arow0, int brow0,
                 f32x4 (&acc)[MF][NF], u16* As, u16* Bs)
{
  const int tid  = threadIdx.x;
  const int lane = tid & 63;
  const int w    = tid >> 6;
  const int wr   = w / WC, wc = w % WC;
  constexpr int NT   = WR * WC * 64;
  constexpr int AISS = (BM * BK * 2) / (NT * 16);
  constexpr int BISS = (BN * BK * 2) / (NT * 16);
  constexpr int ABUF = BM * BK;
  constexpr int BBUF = BN * BK;

  #pragma unroll
  for (int m = 0; m < MF; m++)
    #pragma unroll
    for (int n = 0; n < NF; n++) acc[m][n] = f32x4{0.f, 0.f, 0.f, 0.f};

  const int frow = lane & 15;
  const int fs   = lane >> 4;

  auto stage = [&](int buf, int kt) {
    #pragma unroll
    for (int q = 0; q < AISS; q++) {
      const int boff = q * NT * 16 + tid * 16;
      const int row  = boff / (BK * 2);
      const int slot = (boff % (BK * 2)) >> 4;
      const int kk   = ((slot ^ (row & 7)) << 3);
      gld16(A + (long)(arow0 + row) * lda + kt + kk, As + buf * ABUF + (boff >> 1));
    }
    #pragma unroll
    for (int q = 0; q < BISS; q++) {
      const int boff = q * NT * 16 + tid * 16;
      const int row  = boff / (BK * 2);
      const int slot = (boff % (BK * 2)) >> 4;
      const int kk   = ((slot ^ (row & 7)) << 3);
      gld16(B + (long)(brow0 + row) * ldb + kt + kk, Bs + buf * BBUF + (boff >> 1));
    }
  };

  auto compute = [&](int buf) {
    __builtin_amdgcn_s_setprio(1);
    #pragma unroll
    for (int ks = 0; ks < BK / 32; ++ks) {
      bf16x8 af[MF], bfr[NF];
      #pragma unroll
      for (int m = 0; m < MF; m++) {
        const int row  = wr * (MF * 16) + m * 16 + frow;
        const int slot = (ks * 4 + fs) ^ (row & 7);
        af[m] = *(const bf16x8*)(As + buf * ABUF + row * BK + slot * 8);
      }
      #pragma unroll
      for (int n = 0; n < NF; n++) {
        const int row  = wc * (NF * 16) + n * 16 + frow;
        const int slot = (ks * 4 + fs) ^ (row & 7);
        bfr[n] = *(const bf16x8*)(Bs + buf * BBUF + row * BK + slot * 8);
      }
      #pragma unroll
      for (int m = 0; m < MF; m++)
        #pragma unroll
        for (int n = 0; n < NF; n++)
          acc[m][n] = __builtin_amdgcn_mfma_f32_16x16x32_bf16(af[m], bfr[n], acc[m][n], 0, 0, 0);
    }
    __builtin_amdgcn_s_setprio(0);
  };

  stage(0, 0);
  asm volatile("s_waitcnt vmcnt(0)" ::: "memory");
  __syncthreads();
  int cur = 0;
  for (int kt = BK; kt < K; kt += BK) {
    stage(cur ^ 1, kt);
    compute(cur);
    asm volatile("s_waitcnt vmcnt(0)" ::: "memory");
    __syncthreads();
    cur ^= 1;
  }
  compute(cur);
}

// Per-wave epilogue: stage wave tile into LDS swizzled, coalesced bf16x8 stores
template<int MF, int NF, typename FV, typename FS>
DEV void epi_u16(u16* SH, FV&& fval, FS&& fstore)
{
  constexpr int RC = MF * 16, CC = NF * 16, CPR = NF * 2;
  const int lane = threadIdx.x & 63;
  const int w = threadIdx.x >> 6;
  u16* et = SH + w * (RC * CC);
  __syncthreads();
  #pragma unroll
  for (int m = 0; m < MF; m++)
    #pragma unroll
    for (int n = 0; n < NF; n++)
      #pragma unroll
      for (int j = 0; j < 4; j++) {
        const int row = m * 16 + (lane >> 4) * 4 + j;
        const int col = n * 16 + (lane & 15);
        et[row * CC + (((col >> 3) ^ row) & (CPR - 1)) * 8 + (col & 7)] =
            f2bf(fval(m, n, j, row, col));
      }
  constexpr int RPI = 64 / CPR;
  #pragma unroll
  for (int it = 0; it < RC / RPI; ++it) {
    const int row = it * RPI + lane / CPR;
    const int ch  = lane % CPR;
    bf16x8 v = *(const bf16x8*)(et + row * CC + ((ch ^ row) & (CPR - 1)) * 8);
    fstore(row, ch * 8, v);
  }
}

// ---------------------------------------------------------------------------
// k_prep: blocks 0-3: Ahat[h] = Wk_h @ Wq_h^T; blocks 4-7: MxT = (Wv_h Wo_h)^T
//         blocks 8-71: nh row of MxT (wave-parallel, comparable per-block cost)
__global__ __launch_bounds__(256) void k_prep(
    const u16* __restrict__ Wpb, const u16* __restrict__ Wot,
    const float* __restrict__ bp,
    u16* __restrict__ Ahat, u16* __restrict__ MxT)
{
  __shared__ __align__(16) u16 SH[4 * 64 * 64];
  const int q = blockIdx.x;
  if (q >= 8) {                       // nh: MxT[c'][h*80+64] = bv . Wo[:,c']
    const int p = q - 8;
    const int wv = threadIdx.x >> 6, lane = threadIdx.x & 63;
    const int idx = p * 4 + wv;       // 0..255
    const int h = idx >> 6, cp = idx & 63;
    const u16* wr_ = Wot + (long)cp * 2560 + h * 640;
    const float* bv = bp + h * 1920 + 1280;
    float s = 0.f;
    #pragma unroll
    for (int d0 = 0; d0 < 640; d0 += 64)
      s += bf2f(wr_[d0 + lane]) * bv[d0 + lane];
    #pragma unroll
    for (int off = 32; off; off >>= 1) s += __shfl_down(s, off);
    if (lane == 0) MxT[cp * 320 + h * 80 + 64] = f2bf(s);
    if (lane >= 1 && lane < 16) MxT[cp * 320 + h * 80 + 64 + lane] = 0;
    return;
  }
  u16* As = SH; u16* Bs = SH + 2 * 64 * 64;
  const int w = threadIdx.x >> 6;
  const int wr = w >> 1, wc = w & 1;
  f32x4 acc[2][2];
  if (q < 4) {
    const int h = q;
    gemm_nt<64, 64, 64, 2, 2, 2, 2>(Wpb + h * 1920 + 640, Wpb + h * 1920, 640,
                                    7680, 7680, 0, 0, acc, As, Bs);
    u16* dst = Ahat + h * 4096;
    epi_u16<2, 2>(SH,
      [&](int m, int n, int j, int row, int col){ return acc[m][n][j]; },
      [&](int row, int c0, bf16x8 v){
        *(bf16x8*)(dst + (wr * 32 + row) * 64 + wc * 32 + c0) = v; });
  } else {
    const int h = q - 4;
    gemm_nt<64, 64, 64, 2, 2, 2, 2>(Wot + h * 640, Wpb + h * 1920 + 1280, 640,
                                    2560, 7680, 0, 0, acc, As, Bs);
    epi_u16<2, 2>(SH,
      [&](int m, int n, int j, int row, int col){ return acc[m][n][j]; },
      [&](int row, int c0, bf16x8 v){
        *(bf16x8*)(MxT + (long)(wr * 32 + row) * 320 + h * 80 + wc * 32 + c0) = v; });
  }
}

// ---------------------------------------------------------------------------
// Pass 1: Z[bh][j] = sum_i exp(SCALE*(T_i.x_j + ut_i)). No P store.
// grid 256 = (bh, tj); per block loop over 8 i-tiles, T recomputed in LDS.
__global__ __launch_bounds__(256) void k_qkz(
    const u16* __restrict__ xt, const u16* __restrict__ Ahat,
    const float* __restrict__ uh, float* __restrict__ Z)
{
  __shared__ __align__(16) u16 XI[2][8192];
  __shared__ __align__(16) u16 AH[4096];
  __shared__ __align__(16) u16 XJ[8192];
  __shared__ __align__(16) u16 TT[8192];
  __shared__ float uts[128];
  __shared__ float uhl[64];
  __shared__ float Zs[2][128];
  const int tid = threadIdx.x, lane = tid & 63, w = tid >> 6;
  const int frow = lane & 15, fs = lane >> 4;
  const int wr = w >> 1, wc = w & 1;
  const int id = xcd_swz(256);
  const int bh = id >> 3, tj = id & 7;
  const int b = bh >> 2, h = bh & 3;
  const int j0 = b * 1024 + tj * 128;

  #pragma unroll
  for (int q = 0; q < 2; q++) {       // AH
    const int boff = q * 4096 + tid * 16;
    const int row = boff >> 7, slot = (boff & 127) >> 4;
    const int kk = (slot ^ (row & 7)) << 3;
    gld16(Ahat + h * 4096 + row * 64 + kk, AH + (boff >> 1));
  }
  stage_x64<256>(xt + (long)j0 * 64, XJ, tid);
  stage_x64<256>(xt + (long)(b * 1024) * 64, XI[0], tid);
  if (tid < 64) uhl[tid] = uh[h * 64 + tid];
  asm volatile("s_waitcnt vmcnt(0)" ::: "memory");
  __syncthreads();

  float csum[4] = {0.f, 0.f, 0.f, 0.f};
  int cur = 0;
  for (int it = 0; it < 8; ++it) {
    if (it < 7) stage_x64<256>(xt + (long)(b * 1024 + (it + 1) * 128) * 64, XI[cur ^ 1], tid);
    // T-gemm: T = XI[cur] @ AH^T (wave 64x32)
    f32x4 acc1[4][2];
    #pragma unroll
    for (int m = 0; m < 4; m++)
      #pragma unroll
      for (int n = 0; n < 2; n++) acc1[m][n] = f32x4{0.f, 0.f, 0.f, 0.f};
    #pragma unroll
    for (int ks = 0; ks < 2; ks++) {
      bf16x8 af[4], bfr[2];
      #pragma unroll
      for (int m = 0; m < 4; m++) {
        const int row = wr * 64 + m * 16 + frow;
        af[m] = *(const bf16x8*)(XI[cur] + row * 64 + (((ks * 4 + fs) ^ (row & 7)) << 3));
      }
      #pragma unroll
      for (int n = 0; n < 2; n++) {
        const int row = wc * 32 + n * 16 + frow;
        bfr[n] = *(const bf16x8*)(AH + row * 64 + (((ks * 4 + fs) ^ (row & 7)) << 3));
      }
      #pragma unroll
      for (int m = 0; m < 4; m++)
        #pragma unroll
        for (int n = 0; n < 2; n++)
          acc1[m][n] = __builtin_amdgcn_mfma_f32_16x16x32_bf16(af[m], bfr[n], acc1[m][n], 0, 0, 0);
    }
    float su = 0.f;
    if (tid < 128) {
      #pragma unroll
      for (int s = 0; s < 8; s++) {
        bf16x8 v = *(const bf16x8*)(XI[cur] + tid * 64 + ((s ^ (tid & 7)) << 3));
        #pragma unroll
        for (int e = 0; e < 8; e++) su += bf2f((u16)v[e]) * uhl[s * 8 + e];
      }
    }
    __syncthreads();                 // prev TT/uts reads done
    if (tid < 128) uts[tid] = su;
    #pragma unroll
    for (int m = 0; m < 4; m++)
      #pragma unroll
      for (int n = 0; n < 2; n++)
        #pragma unroll
        for (int j = 0; j < 4; j++) {
          const int row = wr * 64 + m * 16 + (lane >> 4) * 4 + j;
          const int col = wc * 32 + n * 16 + (lane & 15);
          TT[row * 64 + (((col >> 3) ^ (row & 7)) << 3) + (col & 7)] = f2bf(acc1[m][n][j]);
        }
    asm volatile("s_waitcnt vmcnt(0)" ::: "memory");
    __syncthreads();                 // TT/uts visible; XI[cur^1] landed
    // S-gemm + exp + csum
    f32x4 sacc[4][4];
    #pragma unroll
    for (int m = 0; m < 4; m++)
      #pragma unroll
      for (int n = 0; n < 4; n++) sacc[m][n] = f32x4{0.f, 0.f, 0.f, 0.f};
    #pragma unroll
    for (int ks = 0; ks < 2; ks++) {
      bf16x8 af[4], bfr[4];
      #pragma unroll
      for (int m = 0; m < 4; m++) {
        const int row = wr * 64 + m * 16 + frow;
        af[m] = *(const bf16x8*)(TT + row * 64 + (((ks * 4 + fs) ^ (row & 7)) << 3));
      }
      #pragma unroll
      for (int n = 0; n < 4; n++) {
        const int row = wc * 64 + n * 16 + frow;
        bfr[n] = *(const bf16x8*)(XJ + row * 64 + (((ks * 4 + fs) ^ (row & 7)) << 3));
      }
      #pragma unroll
      for (int m = 0; m < 4; m++)
        #pragma unroll
        for (int n = 0; n < 4; n++)
          sacc[m][n] = __builtin_amdgcn_mfma_f32_16x16x32_bf16(af[m], bfr[n], sacc[m][n], 0, 0, 0);
    }
    #pragma unroll
    for (int m = 0; m < 4; m++)
      #pragma unroll
      for (int j = 0; j < 4; j++) {
        const float rv = uts[wr * 64 + m * 16 + (lane >> 4) * 4 + j];
        #pragma unroll
        for (int n = 0; n < 4; n++)
          csum[n] += __expf((sacc[m][n][j] + rv) * 0.03952847075210474f);
      }
    cur ^= 1;
  }
  #pragma unroll
  for (int n = 0; n < 4; n++) {
    csum[n] += __shfl_xor(csum[n], 16);
    csum[n] += __shfl_xor(csum[n], 32);
  }
  if ((lane >> 4) == 0) {
    #pragma unroll
    for (int n = 0; n < 4; n++) Zs[wr][wc * 64 + n * 16 + lane] = csum[n];
  }
  __syncthreads();
  if (tid < 128) Z[(long)bh * 1024 + tj * 128 + tid] = Zs[0][tid] + Zs[1][tid];
}

// ---------------------------------------------------------------------------
// Pass 2: G[b*1024+i][h*80+c] = sum_j (exp(..)/Z[j]) * xb[b][c][j]
// 4 waves (256 threads), grid 256 = (bh, ti).
__global__ __launch_bounds__(256) void k_G(
    const u16* __restrict__ xt, const u16* __restrict__ xb,
    const u16* __restrict__ Ahat, const float* __restrict__ uh,
    const float* __restrict__ Z, u16* __restrict__ G)
{
  __shared__ __align__(16) u16 XIT[8192];    // XI, then T
  __shared__ __align__(16) u16 AH[4096];
  __shared__ __align__(16) u16 XJ[2][8192];
  __shared__ __align__(16) u16 XB[10240];    // [80][128]
  __shared__ __align__(16) u16 PT[16384];    // P-tile [128][128]; then G staging
  __shared__ float uts[128];
  __shared__ float uhl[64];
  __shared__ float rzs[128];
  const int tid = threadIdx.x, lane = tid & 63, w = tid >> 6;
  const int frow = lane & 15, fs = lane >> 4;
  const int wr = w >> 1, wc = w & 1;
  const int id = xcd_swz(256);
  const int bh = id >> 3, ti = id & 7;
  const int b = bh >> 2, h = bh & 3;
  const int i0 = b * 1024 + ti * 128;

  #pragma unroll
  for (int q = 0; q < 2; q++) {       // AH
    const int boff = q * 4096 + tid * 16;
    const int row = boff >> 7, slot = (boff & 127) >> 4;
    const int kk = (slot ^ (row & 7)) << 3;
    gld16(Ahat + h * 4096 + row * 64 + kk, AH + (boff >> 1));
  }
  stage_x64<256>(xt + (long)i0 * 64, XIT, tid);
  stage_x64<256>(xt + (long)(b * 1024) * 64, XJ[0], tid);
  if (tid < 64) uhl[tid] = uh[h * 64 + tid];
  asm volatile("s_waitcnt vmcnt(0)" ::: "memory");
  __syncthreads();

  // T-gemm + ut
  f32x4 acc1[4][2];
  #pragma unroll
  for (int m = 0; m < 4; m++)
    #pragma unroll
    for (int n = 0; n < 2; n++) acc1[m][n] = f32x4{0.f, 0.f, 0.f, 0.f};
  #pragma unroll
  for (int ks = 0; ks < 2; ks++) {
    bf16x8 af[4], bfr[2];
    #pragma unroll
    for (int m = 0; m < 4; m++) {
      const int row = wr * 64 + m * 16 + frow;
      af[m] = *(const bf16x8*)(XIT + row * 64 + (((ks * 4 + fs) ^ (row & 7)) << 3));
    }
    #pragma unroll
    for (int n = 0; n < 2; n++) {
      const int row = wc * 32 + n * 16 + frow;
      bfr[n] = *(const bf16x8*)(AH + row * 64 + (((ks * 4 + fs) ^ (row & 7)) << 3));
    }
    #pragma unroll
    for (int m = 0; m < 4; m++)
      #pragma unroll
      for (int n = 0; n < 2; n++)
        acc1[m][n] = __builtin_amdgcn_mfma_f32_16x16x32_bf16(af[m], bfr[n], acc1[m][n], 0, 0, 0);
  }
  float su = 0.f;
  if (tid < 128) {
    #pragma unroll
    for (int s = 0; s < 8; s++) {
      bf16x8 v = *(const bf16x8*)(XIT + tid * 64 + ((s ^ (tid & 7)) << 3));
      #pragma unroll
      for (int e = 0; e < 8; e++) su += bf2f((u16)v[e]) * uhl[s * 8 + e];
    }
  }
  __syncthreads();                   // all XIT reads done
  if (tid < 128) uts[tid] = su;
  #pragma unroll
  for (int m = 0; m < 4; m++)        // write T over XIT
    #pragma unroll
    for (int n = 0; n < 2; n++)
      #pragma unroll
      for (int j = 0; j < 4; j++) {
        const int row = wr * 64 + m * 16 + (lane >> 4) * 4 + j;
        const int col = wc * 32 + n * 16 + (lane & 15);
        XIT[row * 64 + (((col >> 3) ^ (row & 7)) << 3) + (col & 7)] = f2bf(acc1[m][n][j]);
      }
  __syncthreads();                   // T/uts visible

  f32x4 gacc[2][5];
  #pragma unroll
  for (int m = 0; m < 2; m++)
    #pragma unroll
    for (int n = 0; n < 5; n++) gacc[m][n] = f32x4{0.f, 0.f, 0.f, 0.f};
  int cur = 0;
  for (int j = 0; j < 8; ++j) {
    // stage XB(j): [80][128] from xb[b][c][j*128..]
    #pragma unroll
    for (int q = 0; q < 5; q++) {
      const int boff = q * 4096 + tid * 16;
      const int c = boff >> 8, sl = (boff & 255) >> 4;
      const int kk = (sl ^ (c & 7)) << 3;
      gld16(xb + ((long)b * 80 + c) * 1024 + j * 128 + kk, XB + (boff >> 1));
    }
    if (j < 7) stage_x64<256>(xt + (long)(b * 1024 + (j + 1) * 128) * 64, XJ[cur ^ 1], tid);
    if (tid < 128) rzs[tid] = 1.0f / Z[(long)bh * 1024 + j * 128 + tid];
    // S-gemm: S = T @ XJ[cur]^T (wave 64x64)
    f32x4 sacc[4][4];
    #pragma unroll
    for (int m = 0; m < 4; m++)
      #pragma unroll
      for (int n = 0; n < 4; n++) sacc[m][n] = f32x4{0.f, 0.f, 0.f, 0.f};
    #pragma unroll
    for (int ks = 0; ks < 2; ks++) {
      bf16x8 af[4], bfr[4];
      #pragma unroll
      for (int m = 0; m < 4; m++) {
        const int row = wr * 64 + m * 16 + frow;
        af[m] = *(const bf16x8*)(XIT + row * 64 + (((ks * 4 + fs) ^ (row & 7)) << 3));
      }
      #pragma unroll
      for (int n = 0; n < 4; n++) {
        const int row = wc * 64 + n * 16 + frow;
        bfr[n] = *(const bf16x8*)(XJ[cur] + row * 64 + (((ks * 4 + fs) ^ (row & 7)) << 3));
      }
      #pragma unroll
      for (int m = 0; m < 4; m++)
        #pragma unroll
        for (int n = 0; n < 4; n++)
          sacc[m][n] = __builtin_amdgcn_mfma_f32_16x16x32_bf16(af[m], bfr[n], sacc[m][n], 0, 0, 0);
    }
    __syncthreads();                 // rzs visible; PT free (prev G-gemm done)
    #pragma unroll
    for (int m = 0; m < 4; m++)
      #pragma unroll
      for (int jj = 0; jj < 4; jj++) {
        const int row = wr * 64 + m * 16 + (lane >> 4) * 4 + jj;
        const float rv = uts[row];
        #pragma unroll
        for (int n = 0; n < 4; n++) {
          const int col = wc * 64 + n * 16 + (lane & 15);
          const float p = __expf((sacc[m][n][jj] + rv) * 0.03952847075210474f) * rzs[col];
          PT[row * 128 + (((col >> 3) ^ (row & 7)) << 3) + (col & 7)] = f2bf(p);
        }
      }
    asm volatile("s_waitcnt vmcnt(0)" ::: "memory");   // XB(j), XJ[next] landed
    __syncthreads();                 // P visible
    // G-gemm: gacc += P @ XB^T-view (wave rows w*32..+32, cols 0..79, K=128)
    #pragma unroll
    for (int ks = 0; ks < 4; ks++) {
      bf16x8 af2[2], bfr2[5];
      #pragma unroll
      for (int m = 0; m < 2; m++) {
        const int row = w * 32 + m * 16 + frow;
        af2[m] = *(const bf16x8*)(PT + row * 128 + (((ks * 4 + fs) ^ (row & 7)) << 3));
      }
      #pragma unroll
      for (int n = 0; n < 5; n++) {
        const int rc = n * 16 + frow;
        bfr2[n] = *(const bf16x8*)(XB + rc * 128 + (((ks * 4 + fs) ^ (rc & 7)) << 3));
      }
      #pragma unroll
      for (int m = 0; m < 2; m++)
        #pragma unroll
        for (int n = 0; n < 5; n++)
          gacc[m][n] = __builtin_amdgcn_mfma_f32_16x16x32_bf16(af2[m], bfr2[n], gacc[m][n], 0, 0, 0);
    }
    __syncthreads();                 // all P/XB reads done before overwrite
    cur ^= 1;
  }
  // stage G-tile [128][80] in PT (dead), then coalesced stores
  #pragma unroll
  for (int m = 0; m < 2; m++)
    #pragma unroll
    for (int n = 0; n < 5; n++)
      #pragma unroll
      for (int jj = 0; jj < 4; jj++) {
        const int row = w * 32 + m * 16 + (lane >> 4) * 4 + jj;
        const int col = n * 16 + (lane & 15);
        PT[row * 80 + col] = f2bf(gacc[m][n][jj]);
      }
  __syncthreads();
  #pragma unroll
  for (int it = 0; it < 5; ++it) {
    const int task = it * 256 + tid;
    const int row = task / 10, ch = task % 10;
    bf16x8 v = *(const bf16x8*)(PT + row * 80 + ch * 8);
    *(bf16x8*)(G + (long)(i0 + row) * 320 + h * 80 + ch * 8) = v;
  }
}

// ---------------------------------------------------------------------------
// out[b][c][s] = G @ MxT^T + bo + x  (f32, fused residual, coalesced stores)
// BM=64 -> 128 blocks (2x CU coverage vs BM=128; this kernel is HBM-bound).
__global__ __launch_bounds__(256) void k_out(
    const u16* __restrict__ G, const u16* __restrict__ MxT,
    const float* __restrict__ bo, const float* __restrict__ x, float* __restrict__ out)
{
  __shared__ __align__(16) u16 SH[4 * 64 * 64];   // As+Bs 32 KB; reused as etf
  u16* As = SH; u16* Bs = SH + 2 * 64 * 64;
  f32x4 acc[2][2];
  gemm_nt<64, 64, 64, 2, 2, 2, 2>(G, MxT, 320, 320, 320,
                                  blockIdx.x * 64, 0, acc, As, Bs);
  const int lane = threadIdx.x & 63;
  const int w = threadIdx.x >> 6;
  const int wr = w >> 1, wc = w & 1;
  float* etf = (float*)SH;   // [64 c][68] f32 = 17408 B
  __syncthreads();
  #pragma unroll
  for (int m = 0; m < 2; m++)
    #pragma unroll
    for (int n = 0; n < 2; n++)
      #pragma unroll
      for (int j = 0; j < 4; j++) {
        const int sl = wr * 32 + m * 16 + (lane >> 4) * 4 + j;   // s-local
        const int c  = wc * 32 + n * 16 + (lane & 15);           // channel
        etf[c * 68 + sl] = acc[m][n][j];
      }
  __syncthreads();
  const int b = blockIdx.x >> 4, s0 = (blockIdx.x & 15) * 64;
  #pragma unroll
  for (int it = 0; it < 4; ++it) {
    const int task = it * 256 + threadIdx.x;   // 1024 tasks: 64 c x 16 chunks
    const int c = task >> 4, q = (task & 15) * 4;
    const float bias = bo[c];
    f32x4 v = *(const f32x4*)(etf + c * 68 + q);
    const long xi = ((long)(b * 64 + c) << 10) + s0 + q;
    const f32x4 xv = *(const f32x4*)(x + xi);
    #pragma unroll
    for (int e = 0; e < 4; e++) v[e] += bias + xv[e];
    *(f32x4*)(out + xi) = v;
  }
}

// ---------------------------------------------------------------------------
extern "C" void kernel_launch(void* const* d_in, const int* in_sizes, int n_in,
                              void* d_out, int out_size, void* d_ws, size_t ws_size,
                              hipStream_t stream)
{
  (void)in_sizes; (void)n_in; (void)out_size; (void)ws_size;
  const float* x  = (const float*)d_in[0];
  // d_in[1] = t (unused)
  const float* Wp = (const float*)d_in[2];
  const float* bp = (const float*)d_in[3];
  const float* Wo = (const float*)d_in[4];
  const float* bo = (const float*)d_in[5];
  float* out = (float*)d_out;

  char* w8 = (char*)d_ws;
  u16*   xt   = (u16*)(w8 + 0L);          // [8192][64] bf16, 1 MB
  u16*   xb   = (u16*)(w8 + 1048576L);    // [8][80][1024] bf16
  u16*   Wot  = (u16*)(w8 + 2359296L);    // [64][2560] bf16
  u16*   Wpb  = (u16*)(w8 + 2686976L);    // [64][7680] bf16
  u16*   Ahat = (u16*)(w8 + 3670016L);    // [4][64][64] bf16
  u16*   MxT  = (u16*)(w8 + 3702784L);    // [64][320] bf16
  float* uh   = (float*)(w8 + 3743744L);  // [4][64]
  float* Z    = (float*)(w8 + 3744768L);  // [32][1024] f32
  u16*   G    = (u16*)(w8 + 3875840L);    // [8192][320] bf16, 5 MB

  k_misc<<<792, 256, 0, stream>>>(x, Wp, Wo, bp, xt, Wot, Wpb, xb, uh);
  k_prep<<<72,  256, 0, stream>>>(Wpb, Wot, bp, Ahat, MxT);
  k_qkz <<<256, 256, 0, stream>>>(xt, Ahat, uh, Z);
  k_G   <<<256, 256, 0, stream>>>(xt, xb, Ahat, uh, Z, G);
  k_out <<<128, 256, 0, stream>>>(G, MxT, bo, x, out);
}